// Round 1
// baseline (305.737 us; speedup 1.0000x reference)
//
#include <hip/hip_runtime.h>
#include <cstdint>

#define GRIDW   40
#define SEQ     1600      // 40*40
#define NVOCAB  32
#define PATH_ID 6
#define IGNORE_ID (-100)
#define NWORDS  25        // 1600 / 64
#define BLK     256

// ---------------------------------------------------------------------------
// One block per batch row. Phase 1: stream logits [SEQ,32] (float4 x8 per
// token), compute argmax + log-softmax CE; accumulate per-row ce/count/correct
// and a path (pred==PATH_ID) byte map in LDS. Phase 2: block reductions,
// spatial penalty over consecutive path positions, connected-component count
// via LDS min-label propagation, single atomicAdd of this row's contribution.
// ---------------------------------------------------------------------------
__global__ __launch_bounds__(BLK) void act_loss_kernel(
    const float* __restrict__ logits,   // [B, SEQ, NVOCAB]
    const int*   __restrict__ labels,   // [B, SEQ]
    const float* __restrict__ qhalt,    // [B]
    float*       __restrict__ out,      // [1]
    int B)
{
    const int b   = blockIdx.x;
    const int tid = threadIdx.x;

    __shared__ uint8_t  path[SEQ];
    __shared__ uint16_t lab[SEQ];
    __shared__ uint16_t pos[SEQ];
    __shared__ uint64_t words[NWORDS];
    __shared__ int      offs[NWORDS + 1];
    __shared__ int      npath_s;
    __shared__ float    red_f[BLK];
    __shared__ int      red_i[BLK];
    __shared__ int      red_j[BLK];
    __shared__ int      changed;
    __shared__ float    part_a;   // lm + 0.5*bce for this row

    // ---------------- Phase 1: per-token CE / argmax ----------------
    float ce_sum = 0.0f;
    int   cnt = 0, cor = 0;

    const float* base  = logits + (size_t)b * SEQ * NVOCAB;
    const int*   lbase = labels + (size_t)b * SEQ;

    for (int i = tid; i < SEQ; i += BLK) {
        const float4* p4 = (const float4*)(base + (size_t)i * NVOCAB);
        float x[NVOCAB];
#pragma unroll
        for (int j = 0; j < 8; ++j) {
            float4 v = p4[j];
            x[4*j+0] = v.x; x[4*j+1] = v.y; x[4*j+2] = v.z; x[4*j+3] = v.w;
        }
        int lbl = lbase[i];

        // argmax, first occurrence of max (strict >)
        float m = x[0]; int arg = 0;
#pragma unroll
        for (int j = 1; j < NVOCAB; ++j) {
            if (x[j] > m) { m = x[j]; arg = j; }
        }
        // log-sum-exp
        float s = 0.0f;
#pragma unroll
        for (int j = 0; j < NVOCAB; ++j) s += __expf(x[j] - m);
        float lse = m + __logf(s);

        bool msk  = (lbl != IGNORE_ID);
        int  slbl = (lbl < 0) ? 0 : lbl;
        float xl = 0.0f;
#pragma unroll
        for (int j = 0; j < NVOCAB; ++j) xl = (j == slbl) ? x[j] : xl;

        ce_sum += msk ? (lse - xl) : 0.0f;
        cnt    += msk ? 1 : 0;
        cor    += (msk && arg == lbl) ? 1 : 0;
        path[i] = (arg == PATH_ID) ? 1 : 0;
    }
    __syncthreads();

    // ---------------- block reductions: ce_sum, cnt, cor ----------------
    red_f[tid] = ce_sum; red_i[tid] = cnt; red_j[tid] = cor;
    __syncthreads();
    for (int s = BLK / 2; s > 0; s >>= 1) {
        if (tid < s) {
            red_f[tid] += red_f[tid + s];
            red_i[tid] += red_i[tid + s];
            red_j[tid] += red_j[tid + s];
        }
        __syncthreads();
    }
    if (tid == 0) {
        float ce_tot = red_f[0];
        int   c_tot  = red_i[0];
        int   k_tot  = red_j[0];
        float lm = ce_tot / (float)max(c_tot, 1);
        float t  = (k_tot == c_tot) ? 1.0f : 0.0f;
        float xq = qhalt[b];
        float bce = fmaxf(xq, 0.0f) - xq * t + log1pf(expf(-fabsf(xq)));
        part_a = lm + 0.5f * bce;
    }
    __syncthreads();

    // ---------------- spatial penalty ----------------
    // pack path bytes -> 25 x uint64
    if (tid < NWORDS) {
        uint64_t w = 0;
        int basei = tid * 64;
#pragma unroll 8
        for (int k = 0; k < 64; ++k)
            w |= ((uint64_t)path[basei + k]) << k;
        words[tid] = w;
    }
    __syncthreads();
    if (tid == 0) {
        int o = 0;
        for (int t2 = 0; t2 < NWORDS; ++t2) { offs[t2] = o; o += __popcll(words[t2]); }
        offs[NWORDS] = o;
        npath_s = o;
    }
    __syncthreads();
    if (tid < NWORDS) {
        int o = offs[tid];
        uint64_t w = words[tid];
        int basei = tid * 64;
        while (w) {
            int k = __ffsll((unsigned long long)w) - 1;
            pos[o++] = (uint16_t)(basei + k);
            w &= (w - 1);
        }
    }
    __syncthreads();

    const int np = npath_s;
    int sp_units = 0;
    for (int q = tid; q + 1 < np; q += BLK) {
        int i = pos[q], j = pos[q + 1];
        int dist = abs(i / GRIDW - j / GRIDW) + abs(i % GRIDW - j % GRIDW);
        if (dist > 1) sp_units += dist - 1;
    }

    // ---------------- connectivity: min-label propagation ----------------
    for (int i = tid; i < SEQ; i += BLK)
        lab[i] = path[i] ? (uint16_t)i : (uint16_t)0xFFFF;
    __syncthreads();

    for (;;) {
        if (tid == 0) changed = 0;
        __syncthreads();
        int local = 0;
        for (int i = tid; i < SEQ; i += BLK) {
            if (!path[i]) continue;
            int r = i / GRIDW, c = i % GRIDW;
            uint16_t v = lab[i];
            uint16_t nm = v;
            if (r > 0)          { uint16_t u = lab[i - GRIDW]; nm = (u < nm) ? u : nm; }
            if (r < GRIDW - 1)  { uint16_t u = lab[i + GRIDW]; nm = (u < nm) ? u : nm; }
            if (c > 0)          { uint16_t u = lab[i - 1];     nm = (u < nm) ? u : nm; }
            if (c < GRIDW - 1)  { uint16_t u = lab[i + 1];     nm = (u < nm) ? u : nm; }
            if (nm < v) { lab[i] = nm; local = 1; }
        }
        if (local) changed = 1;   // benign race: all writers write 1
        __syncthreads();
        if (!changed) break;
    }

    int comp = 0;
    for (int i = tid; i < SEQ; i += BLK)
        comp += (path[i] && lab[i] == (uint16_t)i) ? 1 : 0;

    // reduce sp_units and comp
    red_i[tid] = sp_units; red_j[tid] = comp;
    __syncthreads();
    for (int s = BLK / 2; s > 0; s >>= 1) {
        if (tid < s) {
            red_i[tid] += red_i[tid + s];
            red_j[tid] += red_j[tid + s];
        }
        __syncthreads();
    }

    if (tid == 0) {
        int sp_tot   = red_i[0];
        int comp_tot = red_j[0];
        int conn_units = (comp_tot > 1) ? (comp_tot - 1) : 0;
        float total = part_a +
                      ((float)sp_tot * 10.0f + (float)conn_units * 5.0f) / (float)B;
        atomicAdd(out, total);
    }
}

extern "C" void kernel_launch(void* const* d_in, const int* in_sizes, int n_in,
                              void* d_out, int out_size, void* d_ws, size_t ws_size,
                              hipStream_t stream) {
    const float* logits = (const float*)d_in[0];
    const int*   labels = (const int*)d_in[1];
    const float* qhalt  = (const float*)d_in[2];
    // d_in[3] = halted, d_in[4] = steps: metrics-only in reference, unused.
    float* out = (float*)d_out;
    const int B = in_sizes[2];   // q_halt_logits length = batch

    // harness poisons d_out with 0xAA before every launch; we accumulate via
    // atomicAdd, so zero it on-stream first (graph-capture safe).
    hipMemsetAsync(out, 0, (size_t)out_size * sizeof(float), stream);
    act_loss_kernel<<<dim3(B), dim3(BLK), 0, stream>>>(logits, labels, qhalt, out, B);
}